// Round 1
// baseline (508.634 us; speedup 1.0000x reference)
//
#include <hip/hip_runtime.h>

// TBConv2d: BN -> ternary{-1,0,1} -> conv3x3(p=1) -> +bias -> ReLU
// Streaming row-pipeline: block = 32-wide x-strip x 16-row y-chunk.
// 4-row LDS ring of quantized activations [pix][ci] bf16; weights in regs.
//
// v2 changes (occupancy + L2 halo sharing):
//  - YC 32 -> 16: grid 1024 -> 2048 blocks (8 candidates/CU instead of 4)
//  - weight-staging LDS aliased onto the activation ring (weights are dead
//    after the fA register loads): 28.2 KB -> 18.7 KB/block, and
//    __launch_bounds__(256,8) -> 8 resident blocks/CU (32 waves, was 16)
//  - XCD-aware bx encoding: bx%8 == yc&7, so all 8 x-strips of a (b,yc)
//    row-band land on the SAME XCD and run row-locked -> the 64B halo
//    sectors at strip edges are L2 hits instead of duplicate HBM fetches.

#define B_    16
#define H_    256
#define W_    256
#define SW    32
#define YC    16
#define ROWB  2304          // 36 pixel slots (34 real + 2 trash) * 64 B
#define NITEM 576           // 32 ci * 18 float2-pairs per row

typedef __bf16 bf16x8 __attribute__((ext_vector_type(8)));
typedef float  f32x4  __attribute__((ext_vector_type(4)));
union FragCast { int4 i; bf16x8 b; };

__device__ __forceinline__ unsigned short f2bf(float f) {
    union { float f; unsigned u; } c; c.f = f;
    unsigned u = c.u;
    u += 0x7FFFu + ((u >> 16) & 1u);      // RNE
    return (unsigned short)(u >> 16);
}

// torch semantics @thr=0: x <= -0 -> -1 (catches 0), else x >= 0 -> +1, NaN -> 0
__device__ __forceinline__ unsigned short quant1(float v, float sc, float sh) {
    float xh = __fadd_rn(__fmul_rn(v, sc), sh);   // exact numpy op order, no FMA
    return (xh <= 0.0f) ? (unsigned short)0xBF80u
         : ((xh >= 0.0f) ? (unsigned short)0x3F80u : (unsigned short)0u);
}

__launch_bounds__(256, 8)
__global__ void tbconv_kernel(const float* __restrict__ x,
                              const float* __restrict__ bn_g,
                              const float* __restrict__ bn_b,
                              const float* __restrict__ bn_m,
                              const float* __restrict__ bn_v,
                              const float* __restrict__ conv_w,
                              const float* __restrict__ conv_b,
                              float* __restrict__ out)
{
    // Aliased LDS: [0,18432) holds bf16 weights [tap][co][ci] during init,
    // then becomes the 4-row quantized-activation ring [0, 4*ROWB=9216).
    __shared__ __align__(16) unsigned char smem[18432];
    __shared__ float sScale[32], sShift[32];
    unsigned int*  sW = (unsigned int*)smem;
    unsigned char* sQ = smem;

    const int tid = threadIdx.x;
    const int bx  = blockIdx.x;
    // bx = strip*256 + b*16 + yc  ->  bx%8 = yc&7 (XCD id under round-robin):
    // all strips of a (b,yc) band share one XCD/L2.
    const int strip = bx >> 8;
    const int b     = (bx >> 4) & 15;
    const int yc    = bx & 15;
    const int x0 = strip * SW;
    const int y0 = yc * YC;          // multiple of 4 -> ring slots fold to constants

    if (tid < 32) {
        float s = __fdiv_rn(bn_g[tid], __fsqrt_rn(__fadd_rn(bn_v[tid], 1e-4f)));
        sScale[tid] = s;
        sShift[tid] = __fsub_rn(bn_b[tid], __fmul_rn(bn_m[tid], s));
    }
    // stage weights: sW dword j = [t][co][ci-pair]
    for (int j = tid; j < 4608; j += 256) {
        int cp = j & 15, co = (j >> 4) & 31, t = j >> 9;
        float w0 = conv_w[(co * 32 + 2 * cp)     * 9 + t];
        float w1 = conv_w[(co * 32 + 2 * cp + 1) * 9 + t];
        sW[j] = (unsigned)f2bf(w0) | ((unsigned)f2bf(w1) << 16);
    }
    __syncthreads();

    // ---- per-thread loader items: i = (ci, pr); aligned float2 at gx = x0-2+2*pr ----
    const float* lp[3];
    int   lw0[3], lw1[3];
    float lsc[3], lsh[3];
    bool  lxok[3];
    const bool lv2 = (tid < 64);     // third item exists only for wave 0
    #pragma unroll
    for (int j = 0; j < 3; ++j) {
        int i = tid + 256 * j; if (i >= NITEM) i = 0;
        int ci = i / 18, pr = i - 18 * ci;
        int gx = x0 - 2 + 2 * pr;
        bool xok = (gx >= 0) && (gx < W_);       // pairs are all-valid or all-invalid
        int gxc = (gx < 0) ? 0 : ((gx > 254) ? 254 : gx);
        lp[j]   = x + (((size_t)(b * 32 + ci)) << 16) + gxc;
        lxok[j] = xok;
        int hx0 = 2 * pr - 1, hx1 = 2 * pr;      // halo pixel coords of the 2 elements
        int hc0 = (hx0 < 0)  ? 34 : hx0;         // trash slots 34/35 (never read)
        int hc1 = (hx1 > 33) ? 35 : hx1;
        int q = ci >> 3, cl = ci & 7;
        // chunk-level XOR swizzle: phys chunk = hx*4 + (cioct ^ ((hx>>1)&3))
        lw0[j] = ((hc0 * 4 + (q ^ ((hc0 >> 1) & 3))) << 4) + cl * 2;
        lw1[j] = ((hc1 * 4 + (q ^ ((hc1 >> 1) & 3))) << 4) + cl * 2;
        lsc[j] = sScale[ci]; lsh[j] = sShift[ci];
    }

    // ---- wave/tile setup: wave = (ct = co-half, xh = x-half) ----
    const int lane = tid & 63, wave = tid >> 6;
    const int quad = lane >> 4, n = lane & 15;
    const int ct = wave >> 1, xh = wave & 1;
    const int xl = xh * 16 + n;

    // persistent A-frags: A[m=co=ct*16+n][k=ci=quad*8+j] per tap
    FragCast fA[9];
    #pragma unroll
    for (int t = 0; t < 9; ++t)
        fA[t].i = *(const int4*)((const char*)sW + ((t * 32 + ct * 16 + n) * 32 + quad * 8) * 2);

    // per-lane B-frag LDS offsets (y-invariant; slot becomes an immediate)
    int dsoff[3];
    #pragma unroll
    for (int kw = 0; kw < 3; ++kw) {
        int hx = xl + kw;
        dsoff[kw] = (hx * 4 + (quad ^ ((hx >> 1) & 3))) << 4;
    }

    float  bias[4];
    size_t obase[4];
    #pragma unroll
    for (int r = 0; r < 4; ++r) {
        int co = ct * 16 + quad * 4 + r;
        bias[r]  = conv_b[co];
        obase[r] = (((size_t)(b * 32 + co)) << 16) + ((size_t)y0 << 8) + (x0 + xl);
    }

    // all LDS reads of sW / sScale are done -> ring may overwrite the alias
    __syncthreads();

    float2 v[3];
    auto load_row = [&](int gy) {
        bool yok = ((unsigned)gy < (unsigned)H_);
        #pragma unroll
        for (int j = 0; j < 3; ++j) {
            v[j] = make_float2(0.f, 0.f);
            if (yok && (j < 2 || lv2))
                v[j] = *(const float2*)(lp[j] + (gy << 8));
        }
    };
    auto scatter = [&](int gy, int slot) {
        bool yok = ((unsigned)gy < (unsigned)H_);
        char* rowp = (char*)sQ + slot * ROWB;
        #pragma unroll
        for (int j = 0; j < 3; ++j) {
            if (j < 2 || lv2) {
                unsigned short q0 = 0, q1 = 0;
                if (yok && lxok[j]) {
                    q0 = quant1(v[j].x, lsc[j], lsh[j]);
                    q1 = quant1(v[j].y, lsc[j], lsh[j]);
                }
                *(unsigned short*)(rowp + lw0[j]) = q0;   // padding/out-of-range -> 0
                *(unsigned short*)(rowp + lw1[j]) = q1;
            }
        }
    };

    // ---- prologue: quantize rows y0-1..y0+1, prefetch y0+2 ----
    load_row(y0 - 1); scatter(y0 - 1, 3);
    load_row(y0);     scatter(y0,     0);
    load_row(y0 + 1); scatter(y0 + 1, 1);
    load_row(y0 + 2);
    __syncthreads();

    // ---- main loop: 1 output row per step, 1 barrier per step ----
    for (int t8 = 0; t8 < YC / 4; ++t8) {
        #pragma unroll
        for (int u = 0; u < 4; ++u) {
            const int yy = t8 * 4 + u;
            const int y  = y0 + yy;

            f32x4 acc[3];
            #pragma unroll
            for (int kh = 0; kh < 3; ++kh) {
                const int sb = ((u + 3 + kh) & 3) * ROWB;    // slot(y-1+kh), compile-time
                f32x4 a = {0.f, 0.f, 0.f, 0.f};
                #pragma unroll
                for (int kw = 0; kw < 3; ++kw) {
                    FragCast fB;
                    fB.i = *(const int4*)((const char*)sQ + sb + dsoff[kw]);
                    a = __builtin_amdgcn_mfma_f32_16x16x32_bf16(fA[kh * 3 + kw].b, fB.b, a, 0, 0, 0);
                }
                acc[kh] = a;
            }

            if (yy <= YC - 2) scatter(y + 2, (u + 2) & 3);   // uniform guard
            __syncthreads();

            // stores after the barrier: they drain at the NEXT barrier, a full iter away
            #pragma unroll
            for (int r = 0; r < 4; ++r) {
                float s = __fadd_rn(__fadd_rn(acc[0][r], acc[1][r]),
                                    __fadd_rn(acc[2][r], bias[r]));
                out[obase[r] + (yy << 8)] = fmaxf(s, 0.f);
            }
            if (yy <= YC - 3) load_row(y + 3);               // prefetch, consumed next iter
        }
    }
}

extern "C" void kernel_launch(void* const* d_in, const int* in_sizes, int n_in,
                              void* d_out, int out_size, void* d_ws, size_t ws_size,
                              hipStream_t stream) {
    const float* x     = (const float*)d_in[0];
    const float* gamma = (const float*)d_in[1];
    const float* beta  = (const float*)d_in[2];
    const float* mean  = (const float*)d_in[3];
    const float* var   = (const float*)d_in[4];
    const float* w     = (const float*)d_in[5];
    const float* bias  = (const float*)d_in[6];
    float* o = (float*)d_out;

    dim3 grid(B_ * 8 * (H_ / YC));   // 16 batches x 8 x-strips x 16 y-chunks = 2048
    dim3 block(256);
    hipLaunchKernelGGL(tbconv_kernel, grid, block, 0, stream,
                       x, gamma, beta, mean, var, w, bias, o);
}

// Round 2
// 292.432 us; speedup vs baseline: 1.7393x; 1.7393x over previous
//
#include <hip/hip_runtime.h>

// TBConv2d: BN -> ternary{-1,0,1} -> conv3x3(p=1) -> +bias -> ReLU
// Streaming row-pipeline: block = 32-wide x-strip x 16-row y-chunk.
// 4-row LDS ring of quantized activations [pix][ci] bf16; weights in regs.
//
// v3: v2's YC=16 grid + LDS aliasing + XCD halo swizzle, but launch_bounds
// back to (256,4). R1 post-mortem: (256,8) imposed a 64-VGPR hard cap, the
// allocator fell to 32 VGPRs and spilled fA/loader state to scratch
// (FETCH 190->822 MB, WRITE 131->287 MB). Runtime occupancy depends on
// ACTUAL usage: 64 VGPR + 18.9 KB LDS -> 8 blocks/CU even under (256,4).
// Also trimmed ~6 VGPRs (obase[4] -> single base + r<<16 immediates).

#define B_    16
#define H_    256
#define W_    256
#define SW    32
#define YC    16
#define ROWB  2304          // 36 pixel slots (34 real + 2 trash) * 64 B
#define NITEM 576           // 32 ci * 18 float2-pairs per row

typedef __bf16 bf16x8 __attribute__((ext_vector_type(8)));
typedef float  f32x4  __attribute__((ext_vector_type(4)));
union FragCast { int4 i; bf16x8 b; };

__device__ __forceinline__ unsigned short f2bf(float f) {
    union { float f; unsigned u; } c; c.f = f;
    unsigned u = c.u;
    u += 0x7FFFu + ((u >> 16) & 1u);      // RNE
    return (unsigned short)(u >> 16);
}

// torch semantics @thr=0: x <= -0 -> -1 (catches 0), else x >= 0 -> +1, NaN -> 0
__device__ __forceinline__ unsigned short quant1(float v, float sc, float sh) {
    float xh = __fadd_rn(__fmul_rn(v, sc), sh);   // exact numpy op order, no FMA
    return (xh <= 0.0f) ? (unsigned short)0xBF80u
         : ((xh >= 0.0f) ? (unsigned short)0x3F80u : (unsigned short)0u);
}

__launch_bounds__(256, 4)
__global__ void tbconv_kernel(const float* __restrict__ x,
                              const float* __restrict__ bn_g,
                              const float* __restrict__ bn_b,
                              const float* __restrict__ bn_m,
                              const float* __restrict__ bn_v,
                              const float* __restrict__ conv_w,
                              const float* __restrict__ conv_b,
                              float* __restrict__ out)
{
    // Aliased LDS: [0,18432) holds bf16 weights [tap][co][ci] during init,
    // then becomes the 4-row quantized-activation ring [0, 4*ROWB=9216).
    __shared__ __align__(16) unsigned char smem[18432];
    __shared__ float sScale[32], sShift[32];
    unsigned int*  sW = (unsigned int*)smem;
    unsigned char* sQ = smem;

    const int tid = threadIdx.x;
    const int bx  = blockIdx.x;
    // bx = strip*256 + b*16 + yc  ->  bx%8 = yc&7 (XCD id under round-robin):
    // all strips of a (b,yc) band share one XCD/L2.
    const int strip = bx >> 8;
    const int b     = (bx >> 4) & 15;
    const int yc    = bx & 15;
    const int x0 = strip * SW;
    const int y0 = yc * YC;          // multiple of 4 -> ring slots fold to constants

    if (tid < 32) {
        float s = __fdiv_rn(bn_g[tid], __fsqrt_rn(__fadd_rn(bn_v[tid], 1e-4f)));
        sScale[tid] = s;
        sShift[tid] = __fsub_rn(bn_b[tid], __fmul_rn(bn_m[tid], s));
    }
    // stage weights: sW dword j = [t][co][ci-pair]
    for (int j = tid; j < 4608; j += 256) {
        int cp = j & 15, co = (j >> 4) & 31, t = j >> 9;
        float w0 = conv_w[(co * 32 + 2 * cp)     * 9 + t];
        float w1 = conv_w[(co * 32 + 2 * cp + 1) * 9 + t];
        sW[j] = (unsigned)f2bf(w0) | ((unsigned)f2bf(w1) << 16);
    }
    __syncthreads();

    // ---- per-thread loader items: i = (ci, pr); aligned float2 at gx = x0-2+2*pr ----
    const float* lp[3];
    int   lw0[3], lw1[3];
    float lsc[3], lsh[3];
    bool  lxok[3];
    const bool lv2 = (tid < 64);     // third item exists only for wave 0
    #pragma unroll
    for (int j = 0; j < 3; ++j) {
        int i = tid + 256 * j; if (i >= NITEM) i = 0;
        int ci = i / 18, pr = i - 18 * ci;
        int gx = x0 - 2 + 2 * pr;
        bool xok = (gx >= 0) && (gx < W_);       // pairs are all-valid or all-invalid
        int gxc = (gx < 0) ? 0 : ((gx > 254) ? 254 : gx);
        lp[j]   = x + (((size_t)(b * 32 + ci)) << 16) + gxc;
        lxok[j] = xok;
        int hx0 = 2 * pr - 1, hx1 = 2 * pr;      // halo pixel coords of the 2 elements
        int hc0 = (hx0 < 0)  ? 34 : hx0;         // trash slots 34/35 (never read)
        int hc1 = (hx1 > 33) ? 35 : hx1;
        int q = ci >> 3, cl = ci & 7;
        // chunk-level XOR swizzle: phys chunk = hx*4 + (cioct ^ ((hx>>1)&3))
        lw0[j] = ((hc0 * 4 + (q ^ ((hc0 >> 1) & 3))) << 4) + cl * 2;
        lw1[j] = ((hc1 * 4 + (q ^ ((hc1 >> 1) & 3))) << 4) + cl * 2;
        lsc[j] = sScale[ci]; lsh[j] = sShift[ci];
    }

    // ---- wave/tile setup: wave = (ct = co-half, xh = x-half) ----
    const int lane = tid & 63, wave = tid >> 6;
    const int quad = lane >> 4, n = lane & 15;
    const int ct = wave >> 1, xh = wave & 1;
    const int xl = xh * 16 + n;

    // persistent A-frags: A[m=co=ct*16+n][k=ci=quad*8+j] per tap
    FragCast fA[9];
    #pragma unroll
    for (int t = 0; t < 9; ++t)
        fA[t].i = *(const int4*)((const char*)sW + ((t * 32 + ct * 16 + n) * 32 + quad * 8) * 2);

    // per-lane B-frag LDS offsets (y-invariant; slot becomes an immediate)
    int dsoff[3];
    #pragma unroll
    for (int kw = 0; kw < 3; ++kw) {
        int hx = xl + kw;
        dsoff[kw] = (hx * 4 + (quad ^ ((hx >> 1) & 3))) << 4;
    }

    // output base for r=0; rows r=1..3 are +r<<16 (compile-time immediates)
    float bias[4];
    #pragma unroll
    for (int r = 0; r < 4; ++r)
        bias[r] = conv_b[ct * 16 + quad * 4 + r];
    const size_t obase = (((size_t)(b * 32 + ct * 16 + quad * 4)) << 16)
                       + ((size_t)y0 << 8) + (x0 + xl);

    // all LDS reads of sW / sScale are done -> ring may overwrite the alias
    __syncthreads();

    float2 v[3];
    auto load_row = [&](int gy) {
        bool yok = ((unsigned)gy < (unsigned)H_);
        #pragma unroll
        for (int j = 0; j < 3; ++j) {
            v[j] = make_float2(0.f, 0.f);
            if (yok && (j < 2 || lv2))
                v[j] = *(const float2*)(lp[j] + (gy << 8));
        }
    };
    auto scatter = [&](int gy, int slot) {
        bool yok = ((unsigned)gy < (unsigned)H_);
        char* rowp = (char*)sQ + slot * ROWB;
        #pragma unroll
        for (int j = 0; j < 3; ++j) {
            if (j < 2 || lv2) {
                unsigned short q0 = 0, q1 = 0;
                if (yok && lxok[j]) {
                    q0 = quant1(v[j].x, lsc[j], lsh[j]);
                    q1 = quant1(v[j].y, lsc[j], lsh[j]);
                }
                *(unsigned short*)(rowp + lw0[j]) = q0;   // padding/out-of-range -> 0
                *(unsigned short*)(rowp + lw1[j]) = q1;
            }
        }
    };

    // ---- prologue: quantize rows y0-1..y0+1, prefetch y0+2 ----
    load_row(y0 - 1); scatter(y0 - 1, 3);
    load_row(y0);     scatter(y0,     0);
    load_row(y0 + 1); scatter(y0 + 1, 1);
    load_row(y0 + 2);
    __syncthreads();

    // ---- main loop: 1 output row per step, 1 barrier per step ----
    for (int t8 = 0; t8 < YC / 4; ++t8) {
        #pragma unroll
        for (int u = 0; u < 4; ++u) {
            const int yy = t8 * 4 + u;
            const int y  = y0 + yy;

            f32x4 acc[3];
            #pragma unroll
            for (int kh = 0; kh < 3; ++kh) {
                const int sb = ((u + 3 + kh) & 3) * ROWB;    // slot(y-1+kh), compile-time
                f32x4 a = {0.f, 0.f, 0.f, 0.f};
                #pragma unroll
                for (int kw = 0; kw < 3; ++kw) {
                    FragCast fB;
                    fB.i = *(const int4*)((const char*)sQ + sb + dsoff[kw]);
                    a = __builtin_amdgcn_mfma_f32_16x16x32_bf16(fA[kh * 3 + kw].b, fB.b, a, 0, 0, 0);
                }
                acc[kh] = a;
            }

            if (yy <= YC - 2) scatter(y + 2, (u + 2) & 3);   // uniform guard
            __syncthreads();

            // stores after the barrier: they drain at the NEXT barrier, a full iter away
            #pragma unroll
            for (int r = 0; r < 4; ++r) {
                float s = __fadd_rn(__fadd_rn(acc[0][r], acc[1][r]),
                                    __fadd_rn(acc[2][r], bias[r]));
                out[obase + ((size_t)r << 16) + (yy << 8)] = fmaxf(s, 0.f);
            }
            if (yy <= YC - 3) load_row(y + 3);               // prefetch, consumed next iter
        }
    }
}

extern "C" void kernel_launch(void* const* d_in, const int* in_sizes, int n_in,
                              void* d_out, int out_size, void* d_ws, size_t ws_size,
                              hipStream_t stream) {
    const float* x     = (const float*)d_in[0];
    const float* gamma = (const float*)d_in[1];
    const float* beta  = (const float*)d_in[2];
    const float* mean  = (const float*)d_in[3];
    const float* var   = (const float*)d_in[4];
    const float* w     = (const float*)d_in[5];
    const float* bias  = (const float*)d_in[6];
    float* o = (float*)d_out;

    dim3 grid(B_ * 8 * (H_ / YC));   // 16 batches x 8 x-strips x 16 y-chunks = 2048
    dim3 block(256);
    hipLaunchKernelGGL(tbconv_kernel, grid, block, 0, stream,
                       x, gamma, beta, mean, var, w, bias, o);
}

// Round 4
// 290.888 us; speedup vs baseline: 1.7486x; 1.0053x over previous
//
#include <hip/hip_runtime.h>

// TBConv2d: BN -> ternary{-1,0,1} -> conv3x3(p=1) -> +bias -> ReLU
// Streaming row-pipeline: block = 32-wide x-strip x 32-row y-chunk.
// 8-row LDS ring of quantized activations [pix][ci] bf16; weights in regs.
//
// v4 (resubmit after infra failure in R3; kernel audited: uniform barriers,
// disjoint ring read/write sets, in-bounds addressing).
// MLP-depth restructure. R2 post-mortem: traffic is near-ideal
// (FETCH 148 MB = 1.10x compulsory) but BW only 2.3 TB/s -> latency-bound.
// Need ~22 KB/CU of loads in flight for 6.3 TB/s @ ~900cy; old structure
// had 4.6 KB/block with issue->use distance < latency.
//  - YC back to 32 (grid 1024): halves per-block fixed cost (weight staging,
//    prologue) that made YC=16 a regression.
//  - 2 output rows per barrier, 8-row ring (= exactly the 18432 B weight
//    alias). 2 rows (9.2 KB) of global loads in flight per block, issued
//    AFTER the barrier (so the conservative vmcnt-drain at s_barrier never
//    stalls them); consumed by scatter one full iteration later.
//  - 12 ds_reads feed 18 MFMAs (middle rows shared by both output rows);
//    16 barriers/block instead of 32.
//  - prologue issues all 6 initial row-loads back-to-back (one latency).

#define B_    16
#define H_    256
#define W_    256
#define SW    32
#define YC    32
#define ROWB  2304          // 36 pixel slots (34 real + 2 trash) * 64 B
#define NITEM 576           // 32 ci * 18 float2-pairs per row

typedef __bf16 bf16x8 __attribute__((ext_vector_type(8)));
typedef float  f32x4  __attribute__((ext_vector_type(4)));
union FragCast { int4 i; bf16x8 b; };

__device__ __forceinline__ unsigned short f2bf(float f) {
    union { float f; unsigned u; } c; c.f = f;
    unsigned u = c.u;
    u += 0x7FFFu + ((u >> 16) & 1u);      // RNE
    return (unsigned short)(u >> 16);
}

// torch semantics @thr=0: x <= -0 -> -1 (catches 0), else x >= 0 -> +1, NaN -> 0
__device__ __forceinline__ unsigned short quant1(float v, float sc, float sh) {
    float xh = __fadd_rn(__fmul_rn(v, sc), sh);   // exact numpy op order, no FMA
    return (xh <= 0.0f) ? (unsigned short)0xBF80u
         : ((xh >= 0.0f) ? (unsigned short)0x3F80u : (unsigned short)0u);
}

__launch_bounds__(256, 4)
__global__ void tbconv_kernel(const float* __restrict__ x,
                              const float* __restrict__ bn_g,
                              const float* __restrict__ bn_b,
                              const float* __restrict__ bn_m,
                              const float* __restrict__ bn_v,
                              const float* __restrict__ conv_w,
                              const float* __restrict__ conv_b,
                              float* __restrict__ out)
{
    // Aliased LDS: [0,18432) holds bf16 weights [tap][co][ci] during init,
    // then becomes the 8-row quantized-activation ring (8 * ROWB = 18432).
    __shared__ __align__(16) unsigned char smem[18432];
    __shared__ float sScale[32], sShift[32];
    unsigned int*  sW = (unsigned int*)smem;
    unsigned char* sQ = smem;

    const int tid = threadIdx.x;
    const int bx  = blockIdx.x;
    // bx = strip*128 + b*8 + yc  ->  bx%8 = yc (XCD id under round-robin):
    // all 8 x-strips of a (b,yc) band share one XCD/L2 -> x-halo L2 hits.
    const int strip = bx >> 7;
    const int b     = (bx >> 3) & 15;
    const int yc    = bx & 7;
    const int x0 = strip * SW;
    const int y0 = yc * YC;          // multiple of 8 -> ring slots fold to constants

    if (tid < 32) {
        float s = __fdiv_rn(bn_g[tid], __fsqrt_rn(__fadd_rn(bn_v[tid], 1e-4f)));
        sScale[tid] = s;
        sShift[tid] = __fsub_rn(bn_b[tid], __fmul_rn(bn_m[tid], s));
    }
    // stage weights: sW dword j = [t][co][ci-pair]
    for (int j = tid; j < 4608; j += 256) {
        int cp = j & 15, co = (j >> 4) & 31, t = j >> 9;
        float w0 = conv_w[(co * 32 + 2 * cp)     * 9 + t];
        float w1 = conv_w[(co * 32 + 2 * cp + 1) * 9 + t];
        sW[j] = (unsigned)f2bf(w0) | ((unsigned)f2bf(w1) << 16);
    }
    __syncthreads();

    // ---- per-thread loader items: i = (ci, pr); aligned float2 at gx = x0-2+2*pr ----
    const float* lp[3];
    int   lw0[3], lw1[3];
    float lsc[3], lsh[3];
    bool  lxok[3];
    const bool lv2 = (tid < 64);     // third item exists only for wave 0
    #pragma unroll
    for (int j = 0; j < 3; ++j) {
        int i = tid + 256 * j; if (i >= NITEM) i = 0;
        int ci = i / 18, pr = i - 18 * ci;
        int gx = x0 - 2 + 2 * pr;
        bool xok = (gx >= 0) && (gx < W_);       // pairs are all-valid or all-invalid
        int gxc = (gx < 0) ? 0 : ((gx > 254) ? 254 : gx);
        lp[j]   = x + (((size_t)(b * 32 + ci)) << 16) + gxc;
        lxok[j] = xok;
        int hx0 = 2 * pr - 1, hx1 = 2 * pr;      // halo pixel coords of the 2 elements
        int hc0 = (hx0 < 0)  ? 34 : hx0;         // trash slots 34/35 (never read)
        int hc1 = (hx1 > 33) ? 35 : hx1;
        int q = ci >> 3, cl = ci & 7;
        // chunk-level XOR swizzle: phys chunk = hx*4 + (cioct ^ ((hx>>1)&3))
        lw0[j] = ((hc0 * 4 + (q ^ ((hc0 >> 1) & 3))) << 4) + cl * 2;
        lw1[j] = ((hc1 * 4 + (q ^ ((hc1 >> 1) & 3))) << 4) + cl * 2;
        lsc[j] = sScale[ci]; lsh[j] = sShift[ci];
    }

    // ---- wave/tile setup: wave = (ct = co-half, xh = x-half) ----
    const int lane = tid & 63, wave = tid >> 6;
    const int quad = lane >> 4, n = lane & 15;
    const int ct = wave >> 1, xh = wave & 1;
    const int xl = xh * 16 + n;

    // persistent A-frags: A[m=co=ct*16+n][k=ci=quad*8+j] per tap
    FragCast fA[9];
    #pragma unroll
    for (int t = 0; t < 9; ++t)
        fA[t].i = *(const int4*)((const char*)sW + ((t * 32 + ct * 16 + n) * 32 + quad * 8) * 2);

    // per-lane B-frag LDS offsets (y-invariant; slot becomes an immediate)
    int dsoff[3];
    #pragma unroll
    for (int kw = 0; kw < 3; ++kw) {
        int hx = xl + kw;
        dsoff[kw] = (hx * 4 + (quad ^ ((hx >> 1) & 3))) << 4;
    }

    // output base for r=0; rows r=1..3 are +r<<16 (compile-time immediates)
    float bias[4];
    #pragma unroll
    for (int r = 0; r < 4; ++r)
        bias[r] = conv_b[ct * 16 + quad * 4 + r];
    const size_t obase = (((size_t)(b * 32 + ct * 16 + quad * 4)) << 16)
                       + ((size_t)y0 << 8) + (x0 + xl);

    // all LDS reads of sW / sScale are done -> ring may overwrite the alias
    __syncthreads();

    auto load_row = [&](float2 (&dv)[3], int gy) {
        bool yok = ((unsigned)gy < (unsigned)H_);
        #pragma unroll
        for (int j = 0; j < 3; ++j) {
            dv[j] = make_float2(0.f, 0.f);
            if (yok && (j < 2 || lv2))
                dv[j] = *(const float2*)(lp[j] + (gy << 8));
        }
    };
    auto scatter = [&](const float2 (&sv)[3], int gy, int slot) {
        bool yok = ((unsigned)gy < (unsigned)H_);
        char* rowp = (char*)sQ + slot * ROWB;
        #pragma unroll
        for (int j = 0; j < 3; ++j) {
            if (j < 2 || lv2) {
                unsigned short q0 = 0, q1 = 0;
                if (yok && lxok[j]) {
                    q0 = quant1(sv[j].x, lsc[j], lsh[j]);
                    q1 = quant1(sv[j].y, lsc[j], lsh[j]);
                }
                *(unsigned short*)(rowp + lw0[j]) = q0;   // padding/out-of-range -> 0
                *(unsigned short*)(rowp + lw1[j]) = q1;
            }
        }
    };

    // ---- prologue: issue 6 row-loads back-to-back, scatter rows y0-1..y0+2,
    //      keep rows y0+3, y0+4 in v for iter 0 ----
    float2 v[2][3];
    {
        float2 p0[3], p1[3], p2[3], p3[3];
        load_row(p0, y0 - 1); load_row(p1, y0);
        load_row(p2, y0 + 1); load_row(p3, y0 + 2);
        load_row(v[0], y0 + 3); load_row(v[1], y0 + 4);
        scatter(p0, y0 - 1, 7); scatter(p1, y0, 0);
        scatter(p2, y0 + 1, 1); scatter(p3, y0 + 2, 2);
    }
    __syncthreads();

    // ---- main loop: 2 output rows per barrier, 16 iterations ----
    for (int t4 = 0; t4 < 4; ++t4) {
        #pragma unroll
        for (int u = 0; u < 4; ++u) {
            const int yy = t4 * 8 + u * 2;
            const int y  = y0 + yy;

            // scatter the 2 rows loaded last iteration (slots y+3, y+4)
            if (yy <= 28) {
                scatter(v[0], y + 3, (2 * u + 3) & 7);
                scatter(v[1], y + 4, (2 * u + 4) & 7);
            }
            __syncthreads();

            // issue next 2 row-loads AFTER the barrier: in flight across the
            // whole compute+store phase, consumed by next iter's scatter
            if (yy <= 26) {
                load_row(v[0], y + 5);
                load_row(v[1], y + 6);
            }

            // compute rows y, y+1: 4 LDS rows, 12 ds_reads, 18 MFMAs
            f32x4 aA[3], aB[3];
            #pragma unroll
            for (int kh = 0; kh < 3; ++kh) {
                aA[kh] = (f32x4){0.f, 0.f, 0.f, 0.f};
                aB[kh] = (f32x4){0.f, 0.f, 0.f, 0.f};
            }
            #pragma unroll
            for (int j = 0; j < 4; ++j) {
                const int sb = ((2 * u + 7 + j) & 7) * ROWB;   // slot(y-1+j), compile-time
                FragCast fB[3];
                #pragma unroll
                for (int kw = 0; kw < 3; ++kw)
                    fB[kw].i = *(const int4*)((const char*)sQ + sb + dsoff[kw]);
                #pragma unroll
                for (int kw = 0; kw < 3; ++kw) {
                    if (j < 3)
                        aA[j] = __builtin_amdgcn_mfma_f32_16x16x32_bf16(
                                    fA[j * 3 + kw].b, fB[kw].b, aA[j], 0, 0, 0);
                    if (j >= 1)
                        aB[j - 1] = __builtin_amdgcn_mfma_f32_16x16x32_bf16(
                                    fA[(j - 1) * 3 + kw].b, fB[kw].b, aB[j - 1], 0, 0, 0);
                }
            }

            // stores (drain by the next barrier, a full iteration away)
            #pragma unroll
            for (int r = 0; r < 4; ++r) {
                float sA = __fadd_rn(__fadd_rn(aA[0][r], aA[1][r]),
                                     __fadd_rn(aA[2][r], bias[r]));
                out[obase + ((size_t)r << 16) + ((size_t)yy << 8)] = fmaxf(sA, 0.f);
                float sB = __fadd_rn(__fadd_rn(aB[0][r], aB[1][r]),
                                     __fadd_rn(aB[2][r], bias[r]));
                out[obase + ((size_t)r << 16) + ((size_t)(yy + 1) << 8)] = fmaxf(sB, 0.f);
            }
        }
    }
}

extern "C" void kernel_launch(void* const* d_in, const int* in_sizes, int n_in,
                              void* d_out, int out_size, void* d_ws, size_t ws_size,
                              hipStream_t stream) {
    const float* x     = (const float*)d_in[0];
    const float* gamma = (const float*)d_in[1];
    const float* beta  = (const float*)d_in[2];
    const float* mean  = (const float*)d_in[3];
    const float* var   = (const float*)d_in[4];
    const float* w     = (const float*)d_in[5];
    const float* bias  = (const float*)d_in[6];
    float* o = (float*)d_out;

    dim3 grid(B_ * 8 * (H_ / YC));   // 16 batches x 8 x-strips x 8 y-chunks = 1024
    dim3 block(256);
    hipLaunchKernelGGL(tbconv_kernel, grid, block, 0, stream,
                       x, gamma, beta, mean, var, w, bias, o);
}

// Round 5
// 284.087 us; speedup vs baseline: 1.7904x; 1.0239x over previous
//
#include <hip/hip_runtime.h>

// TBConv2d: BN -> ternary{-1,0,1} -> conv3x3(p=1) -> +bias -> ReLU
// Streaming row-pipeline: block = 32-wide x-strip x 32-row y-chunk.
// 16-row LDS ring of quantized activations [pix][ci] bf16; weights in regs.
//
// v5: kill the per-barrier vmcnt(0) drain. R4 post-mortem: avg in-flight
// bytes = BW*latency = ~3.5 KB/CU (vs 37 KB issued) -> __syncthreads()'s
// implicit s_waitcnt vmcnt(0) drains prefetch loads AND output stores at
// every barrier; all 1024 blocks burst->drain->idle in lockstep (2.4 TB/s).
//  - main-loop barriers: s_waitcnt lgkmcnt(0) + raw s_barrier (LDS
//    visibility only). Loads stay in flight ACROSS barriers; compiler
//    emits counted vmcnt for the scatter's register deps; stores never
//    waited.
//  - ring 8 -> 16 slots (36.9 KB LDS, weights aliased inside): scatter
//    writes slots {2k+7,2k+8}, compute reads {2k-1..2k+2} - disjoint
//    mod 16 across adjacent barrier intervals (verified both directions).
//  - row-pair prefetch double-buffered (vE/vO, compile-time ping-pong on
//    unrolled parity): issue at iter top, consume at next iter top.
//  - prologue pipelined 2-rows-at-a-time (fixes the 19 MB scratch spill
//    seen in R4: WRITE 153 MB vs 134 MB output).

#define B_    16
#define H_    256
#define W_    256
#define SW    32
#define YC    32
#define ROWB  2304          // 36 pixel slots (34 real + 2 trash) * 64 B
#define NITEM 576           // 32 ci * 18 float2-pairs per row

typedef __bf16 bf16x8 __attribute__((ext_vector_type(8)));
typedef float  f32x4  __attribute__((ext_vector_type(4)));
union FragCast { int4 i; bf16x8 b; };

__device__ __forceinline__ unsigned short f2bf(float f) {
    union { float f; unsigned u; } c; c.f = f;
    unsigned u = c.u;
    u += 0x7FFFu + ((u >> 16) & 1u);      // RNE
    return (unsigned short)(u >> 16);
}

// torch semantics @thr=0: x <= -0 -> -1 (catches 0), else x >= 0 -> +1, NaN -> 0
__device__ __forceinline__ unsigned short quant1(float v, float sc, float sh) {
    float xh = __fadd_rn(__fmul_rn(v, sc), sh);   // exact numpy op order, no FMA
    return (xh <= 0.0f) ? (unsigned short)0xBF80u
         : ((xh >= 0.0f) ? (unsigned short)0x3F80u : (unsigned short)0u);
}

// light barrier: LDS visibility only -- does NOT drain vmcnt (prefetch loads
// and output stores stay in flight). "memory" clobbers pin LDS op order.
__device__ __forceinline__ void lds_barrier() {
    asm volatile("s_waitcnt lgkmcnt(0)" ::: "memory");
    __builtin_amdgcn_s_barrier();
}

__launch_bounds__(256, 4)
__global__ void tbconv_kernel(const float* __restrict__ x,
                              const float* __restrict__ bn_g,
                              const float* __restrict__ bn_b,
                              const float* __restrict__ bn_m,
                              const float* __restrict__ bn_v,
                              const float* __restrict__ conv_w,
                              const float* __restrict__ conv_b,
                              float* __restrict__ out)
{
    // Aliased LDS: [0,18432) holds bf16 weights [tap][co][ci] during init,
    // then the whole region becomes the 16-row ring (16 * ROWB = 36864).
    __shared__ __align__(16) unsigned char smem[16 * ROWB];
    __shared__ float sScale[32], sShift[32];
    unsigned int*  sW = (unsigned int*)smem;
    unsigned char* sQ = smem;

    const int tid = threadIdx.x;
    const int bx  = blockIdx.x;
    // bx = strip*128 + b*8 + yc  ->  bx%8 = yc (XCD id under round-robin):
    // all 8 x-strips of a (b,yc) band share one XCD/L2 -> x-halo L2 hits.
    const int strip = bx >> 7;
    const int b     = (bx >> 3) & 15;
    const int yc    = bx & 7;
    const int x0 = strip * SW;
    const int y0 = yc * YC;          // multiple of 32 -> ring slots fold to constants

    if (tid < 32) {
        float s = __fdiv_rn(bn_g[tid], __fsqrt_rn(__fadd_rn(bn_v[tid], 1e-4f)));
        sScale[tid] = s;
        sShift[tid] = __fsub_rn(bn_b[tid], __fmul_rn(bn_m[tid], s));
    }
    // stage weights: sW dword j = [t][co][ci-pair]
    for (int j = tid; j < 4608; j += 256) {
        int cp = j & 15, co = (j >> 4) & 31, t = j >> 9;
        float w0 = conv_w[(co * 32 + 2 * cp)     * 9 + t];
        float w1 = conv_w[(co * 32 + 2 * cp + 1) * 9 + t];
        sW[j] = (unsigned)f2bf(w0) | ((unsigned)f2bf(w1) << 16);
    }
    __syncthreads();

    // ---- per-thread loader items: i = (ci, pr); aligned float2 at gx = x0-2+2*pr ----
    const float* lp[3];
    int   lw0[3], lw1[3];
    float lsc[3], lsh[3];
    bool  lxok[3];
    const bool lv2 = (tid < 64);     // third item exists only for wave 0
    #pragma unroll
    for (int j = 0; j < 3; ++j) {
        int i = tid + 256 * j; if (i >= NITEM) i = 0;
        int ci = i / 18, pr = i - 18 * ci;
        int gx = x0 - 2 + 2 * pr;
        bool xok = (gx >= 0) && (gx < W_);       // pairs are all-valid or all-invalid
        int gxc = (gx < 0) ? 0 : ((gx > 254) ? 254 : gx);
        lp[j]   = x + (((size_t)(b * 32 + ci)) << 16) + gxc;
        lxok[j] = xok;
        int hx0 = 2 * pr - 1, hx1 = 2 * pr;      // halo pixel coords of the 2 elements
        int hc0 = (hx0 < 0)  ? 34 : hx0;         // trash slots 34/35 (never read)
        int hc1 = (hx1 > 33) ? 35 : hx1;
        int q = ci >> 3, cl = ci & 7;
        // chunk-level XOR swizzle: phys chunk = hx*4 + (cioct ^ ((hx>>1)&3))
        lw0[j] = ((hc0 * 4 + (q ^ ((hc0 >> 1) & 3))) << 4) + cl * 2;
        lw1[j] = ((hc1 * 4 + (q ^ ((hc1 >> 1) & 3))) << 4) + cl * 2;
        lsc[j] = sScale[ci]; lsh[j] = sShift[ci];
    }

    // ---- wave/tile setup: wave = (ct = co-half, xh = x-half) ----
    const int lane = tid & 63, wave = tid >> 6;
    const int quad = lane >> 4, n = lane & 15;
    const int ct = wave >> 1, xh = wave & 1;
    const int xl = xh * 16 + n;

    // persistent A-frags: A[m=co=ct*16+n][k=ci=quad*8+j] per tap
    FragCast fA[9];
    #pragma unroll
    for (int t = 0; t < 9; ++t)
        fA[t].i = *(const int4*)((const char*)sW + ((t * 32 + ct * 16 + n) * 32 + quad * 8) * 2);

    // per-lane B-frag LDS offsets (y-invariant; slot becomes an immediate)
    int dsoff[3];
    #pragma unroll
    for (int kw = 0; kw < 3; ++kw) {
        int hx = xl + kw;
        dsoff[kw] = (hx * 4 + (quad ^ ((hx >> 1) & 3))) << 4;
    }

    // output base for r=0; rows r=1..3 are +r<<16 (compile-time immediates)
    float bias[4];
    #pragma unroll
    for (int r = 0; r < 4; ++r)
        bias[r] = conv_b[ct * 16 + quad * 4 + r];
    const size_t obase = (((size_t)(b * 32 + ct * 16 + quad * 4)) << 16)
                       + ((size_t)y0 << 8) + (x0 + xl);

    // all LDS reads of sW / sScale-broadcast are done -> ring may overwrite
    __syncthreads();

    auto load_row = [&](float2 (&dv)[3], int gy) {
        bool yok = ((unsigned)gy < (unsigned)H_);
        #pragma unroll
        for (int j = 0; j < 3; ++j) {
            dv[j] = make_float2(0.f, 0.f);
            if (yok && (j < 2 || lv2))
                dv[j] = *(const float2*)(lp[j] + (gy << 8));
        }
    };
    auto scatter = [&](const float2 (&sv)[3], int gy, int slot) {
        bool yok = ((unsigned)gy < (unsigned)H_);
        char* rowp = (char*)sQ + slot * ROWB;
        #pragma unroll
        for (int j = 0; j < 3; ++j) {
            if (j < 2 || lv2) {
                unsigned short q0 = 0, q1 = 0;
                if (yok && lxok[j]) {
                    q0 = quant1(sv[j].x, lsc[j], lsh[j]);
                    q1 = quant1(sv[j].y, lsc[j], lsh[j]);
                }
                *(unsigned short*)(rowp + lw0[j]) = q0;   // padding/out-of-range -> 0
                *(unsigned short*)(rowp + lw1[j]) = q1;
            }
        }
    };

    // ---- prologue: fill LDS rows rel -1..4 (slots 15,0,1,2,3,4), leave
    //      rows rel 5,6 in vE. Pipelined 2-at-a-time: <=4 rows live. ----
    float2 vE[2][3], vO[2][3];
    {
        float2 pA[2][3], pB[2][3];
        load_row(pA[0], y0 - 1); load_row(pA[1], y0);
        load_row(pB[0], y0 + 1); load_row(pB[1], y0 + 2);
        scatter(pA[0], y0 - 1, 15); scatter(pA[1], y0, 0);
        load_row(pA[0], y0 + 3); load_row(pA[1], y0 + 4);
        scatter(pB[0], y0 + 1, 1); scatter(pB[1], y0 + 2, 2);
        load_row(vE[0], y0 + 5); load_row(vE[1], y0 + 6);
        scatter(pA[0], y0 + 3, 3); scatter(pA[1], y0 + 4, 4);
    }
    lds_barrier();   // vE loads remain in flight

    // ---- main loop: 2 output rows per barrier, 16 iterations (k=t2*8+u).
    //      iter k: issue loads rows 2k+7,2k+8 (other buffer); scatter rows
    //      2k+5,2k+6 (this buffer); barrier; compute rows 2k,2k+1. ----
    for (int t2 = 0; t2 < 2; ++t2) {
        #pragma unroll
        for (int u = 0; u < 8; ++u) {
            const int k  = t2 * 8 + u;
            const int y  = y0 + 2 * k;

            // step 1: issue next pair (into the buffer NOT scattered below)
            if (k <= 12) {
                if ((u & 1) == 0) { load_row(vO[0], y + 7); load_row(vO[1], y + 8); }
                else              { load_row(vE[0], y + 7); load_row(vE[1], y + 8); }
            }
            // step 2: scatter current pair (loaded at iter k-1; counted vmcnt)
            if (k <= 13) {
                if ((u & 1) == 0) {
                    scatter(vE[0], y + 5, (2 * u + 5)  & 15);
                    scatter(vE[1], y + 6, (2 * u + 6)  & 15);
                } else {
                    scatter(vO[0], y + 5, (2 * u + 5)  & 15);
                    scatter(vO[1], y + 6, (2 * u + 6)  & 15);
                }
            }
            // step 3: LDS-visibility barrier only -- no vmcnt drain
            lds_barrier();

            // step 4: compute rows y, y+1: 4 LDS rows, 12 ds_reads, 18 MFMAs
            f32x4 aA[3], aB[3];
            #pragma unroll
            for (int kh = 0; kh < 3; ++kh) {
                aA[kh] = (f32x4){0.f, 0.f, 0.f, 0.f};
                aB[kh] = (f32x4){0.f, 0.f, 0.f, 0.f};
            }
            #pragma unroll
            for (int j = 0; j < 4; ++j) {
                const int sb = ((2 * u + 15 + j) & 15) * ROWB;  // slot(y-1+j), compile-time
                FragCast fB[3];
                #pragma unroll
                for (int kw = 0; kw < 3; ++kw)
                    fB[kw].i = *(const int4*)((const char*)sQ + sb + dsoff[kw]);
                #pragma unroll
                for (int kw = 0; kw < 3; ++kw) {
                    if (j < 3)
                        aA[j] = __builtin_amdgcn_mfma_f32_16x16x32_bf16(
                                    fA[j * 3 + kw].b, fB[kw].b, aA[j], 0, 0, 0);
                    if (j >= 1)
                        aB[j - 1] = __builtin_amdgcn_mfma_f32_16x16x32_bf16(
                                    fA[(j - 1) * 3 + kw].b, fB[kw].b, aB[j - 1], 0, 0, 0);
                }
            }

            // stores: never waited on (no one reads out; no vmcnt drain left)
            #pragma unroll
            for (int r = 0; r < 4; ++r) {
                float sA = __fadd_rn(__fadd_rn(aA[0][r], aA[1][r]),
                                     __fadd_rn(aA[2][r], bias[r]));
                out[obase + ((size_t)r << 16) + ((size_t)(2 * k) << 8)] = fmaxf(sA, 0.f);
                float sB = __fadd_rn(__fadd_rn(aB[0][r], aB[1][r]),
                                     __fadd_rn(aB[2][r], bias[r]));
                out[obase + ((size_t)r << 16) + ((size_t)(2 * k + 1) << 8)] = fmaxf(sB, 0.f);
            }
        }
    }
}

extern "C" void kernel_launch(void* const* d_in, const int* in_sizes, int n_in,
                              void* d_out, int out_size, void* d_ws, size_t ws_size,
                              hipStream_t stream) {
    const float* x     = (const float*)d_in[0];
    const float* gamma = (const float*)d_in[1];
    const float* beta  = (const float*)d_in[2];
    const float* mean  = (const float*)d_in[3];
    const float* var   = (const float*)d_in[4];
    const float* w     = (const float*)d_in[5];
    const float* bias  = (const float*)d_in[6];
    float* o = (float*)d_out;

    dim3 grid(B_ * 8 * (H_ / YC));   // 16 batches x 8 x-strips x 8 y-chunks = 1024
    dim3 block(256);
    hipLaunchKernelGGL(tbconv_kernel, grid, block, 0, stream,
                       x, gamma, beta, mean, var, w, bias, o);
}